// Round 6
// baseline (313.359 us; speedup 1.0000x reference)
//
#include <hip/hip_runtime.h>

#define TT 12
#define DD 96
#define WW 96
#define PLANE (DD*WW)      // 9216
#define SP (TT*PLANE)      // 110592
#define F 64

typedef short bf16x8 __attribute__((ext_vector_type(8)));
typedef short bf16x4 __attribute__((ext_vector_type(4)));
typedef float f32x4  __attribute__((ext_vector_type(4)));

__device__ __forceinline__ float sigmoidf_fast(float x){
    return 1.0f / (1.0f + __expf(-x));
}
__device__ __forceinline__ float tanhf_fast(float x){
    x = fminf(15.0f, fmaxf(-15.0f, x));
    float e = __expf(2.0f * x);
    return (e - 1.0f) / (e + 1.0f);
}
__device__ __forceinline__ unsigned short f2bf(float x){
    unsigned int u = __float_as_uint(x);
    u = (u + 0x7FFFu + ((u >> 16) & 1u)) >> 16;   // RNE
    return (unsigned short)u;
}
__device__ __forceinline__ float bf2f(unsigned short u){
    return __uint_as_float(((unsigned int)u) << 16);
}
// HW packed f32x2 -> bf16x2 (RNE), 1 instr (guide T12, gfx950-verified)
__device__ __forceinline__ unsigned int cvt_pk_bf16(float lo, float hi){
    unsigned int r;
    asm("v_cvt_pk_bf16_f32 %0, %1, %2" : "=v"(r) : "v"(lo), "v"(hi));
    return r;
}

// ===========================================================================
// h transpose: f32 [c][p] -> bf16 [p][c]. LDS 64x65 f32 tile.
// ===========================================================================
__global__ __launch_bounds__(256) void transpose_h(
    const float* __restrict__ h, unsigned short* __restrict__ hT)
{
    __shared__ float tile[64 * 65];
    const int tid  = threadIdx.x;
    const int wv   = tid >> 6;
    const int lane = tid & 63;
    const int p0   = blockIdx.x * 64;

    #pragma unroll
    for (int cc = 0; cc < 16; cc++) {
        const int c = cc * 4 + wv;
        tile[lane * 65 + c] = h[(size_t)c * SP + p0 + lane];
    }
    __syncthreads();
    #pragma unroll
    for (int k = 0; k < 2; k++) {
        const int p  = (tid >> 3) + k * 32;
        const int c0 = (tid & 7) * 8;
        bf16x8 v;
        #pragma unroll
        for (int i = 0; i < 8; i++)
            v[i] = (short)f2bf(tile[p * 65 + c0 + i]);
        *(bf16x8*)(hT + (size_t)(p0 + p) * 64 + c0) = v;
    }
}

// ===========================================================================
// Repack kernels (every call; tiny).
// ===========================================================================
__global__ __launch_bounds__(256) void repack_lru_frag(
    const float* __restrict__ wih, const float* __restrict__ whh,
    unsigned short* __restrict__ awp)
{
    const int idx  = blockIdx.x * 256 + threadIdx.x;  // 49152
    const int j    = idx & 7;
    const int lane = (idx >> 3) & 63;
    const int frag = idx >> 9;
    const int ks   = frag & 1;
    const int t    = (frag >> 1) % 12;
    const int fhi  = frag / 24;
    const int g    = (t < 6) ? t : t - 6;
    const int m    = g * 64 + fhi * 16 + (lane & 15);
    const int kk   = ks * 32 + (lane >> 4) * 8 + j;
    const float v  = (t < 6) ? wih[m * F + kk] : whh[m * F + kk];
    awp[idx] = f2bf(v);
}

__global__ __launch_bounds__(256) void repack_sp_frag(
    const float* __restrict__ wgt, unsigned short* __restrict__ afr)
{
    const int idx  = blockIdx.x * 256 + threadIdx.x;  // 36864
    const int j    = idx & 7;
    const int lane = (idx >> 3) & 63;
    const int frag = idx >> 9;
    const int fhi  = frag & 3;
    const int cl   = (frag >> 2) & 1;
    const int tap  = frag >> 3;
    const int f    = fhi * 16 + (lane & 15);
    const int c    = cl * 32 + (lane >> 4) * 8 + j;
    afr[idx] = f2bf(wgt[(f * 64 + c) * 9 + tap]);
}

__global__ __launch_bounds__(256) void repack_tm_frag(
    const float* __restrict__ wgt, unsigned short* __restrict__ afr)
{
    const int idx  = blockIdx.x * 256 + threadIdx.x;  // 12288
    const int j    = idx & 7;
    const int lane = (idx >> 3) & 63;
    const int frag = idx >> 9;
    const int fhi  = frag & 3;
    const int cl   = (frag >> 2) & 1;
    const int dt   = frag >> 3;
    const int f    = fhi * 16 + (lane & 15);
    const int c    = cl * 32 + (lane >> 4) * 8 + j;
    afr[idx] = f2bf(wgt[(f * 64 + c) * 3 + dt]);
}

__global__ __launch_bounds__(256) void repack_sp4(
    const float* __restrict__ wgt, float* __restrict__ wp)
{
    const int idx = blockIdx.x * 256 + threadIdx.x;  // 2304
    if (idx >= 4 * 9 * 64) return;
    const int f = idx & 63;
    const int tap = (idx >> 6) % 9;
    const int c = idx / (9 * 64);
    wp[idx] = wgt[((f * 4) + c) * 9 + tap];
}

// ===========================================================================
// First conv: CIN=4, f32 [c][p] input, scalar FMA, bf16 [p][c] output, relu.
// ===========================================================================
__global__ __launch_bounds__(256) void conv_spatial_in(
    const float* __restrict__ x, const float* __restrict__ wp,
    const float* __restrict__ bias, unsigned short* __restrict__ out)
{
    const int p  = blockIdx.x * 256 + threadIdx.x;
    const int f0 = blockIdx.y * 16;
    const int t  = p / PLANE;
    const int r  = p - t * PLANE;
    const int d  = r / WW;
    const int w  = r - d * WW;
    const int dm = (d > 0    ? d - 1 : 0);
    const int dp = (d < DD-1 ? d + 1 : DD-1);
    const int wm = (w > 0    ? w - 1 : 0);
    const int wpx= (w < WW-1 ? w + 1 : WW-1);

    float acc[16];
    #pragma unroll
    for (int j = 0; j < 16; j++) acc[j] = 0.f;

    const int base = t * PLANE;
    for (int c = 0; c < 4; c++) {
        const float* ip = x + c * SP + base;
        const float v0 = ip[dm*WW+wm], v1 = ip[dm*WW+w], v2 = ip[dm*WW+wpx];
        const float v3 = ip[d *WW+wm], v4 = ip[d *WW+w], v5 = ip[d *WW+wpx];
        const float v6 = ip[dp*WW+wm], v7 = ip[dp*WW+w], v8 = ip[dp*WW+wpx];
        const float* wr = wp + c * 9 * 64 + f0;
        #pragma unroll
        for (int j = 0; j < 16; j++) {
            acc[j] += v0*wr[0*64+j] + v1*wr[1*64+j] + v2*wr[2*64+j]
                    + v3*wr[3*64+j] + v4*wr[4*64+j] + v5*wr[5*64+j]
                    + v6*wr[6*64+j] + v7*wr[7*64+j] + v8*wr[8*64+j];
        }
    }
    unsigned int pk[4];
    #pragma unroll
    for (int q = 0; q < 4; q++) {
        const float a = fmaxf(acc[q*2+0] + bias[f0 + q*2+0], 0.f);
        const float b = fmaxf(acc[q*2+1] + bias[f0 + q*2+1], 0.f);
        pk[q] = cvt_pk_bf16(a, b);
    }
    // wait: pk order above maps q*2 pairs -> channels f0+0..7 via pk[0..3]
    *(uint4*)(out + (size_t)p * 64 + f0) = make_uint4(pk[0], pk[1], pk[2], pk[3]);
    unsigned int pk2[4];
    #pragma unroll
    for (int q = 0; q < 4; q++) {
        const float a = fmaxf(acc[8 + q*2+0] + bias[f0 + 8 + q*2+0], 0.f);
        const float b = fmaxf(acc[8 + q*2+1] + bias[f0 + 8 + q*2+1], 0.f);
        pk2[q] = cvt_pk_bf16(a, b);
    }
    *(uint4*)(out + (size_t)p * 64 + f0 + 8) = make_uint4(pk2[0], pk2[1], pk2[2], pk2[3]);
}

// ===========================================================================
// Spatial 3x3 conv via MFMA, edge clamp, bias+relu. bf16 [p][c] in/out.
// ===========================================================================
__global__ __launch_bounds__(256) void conv_sp_mfma(
    const unsigned short* __restrict__ in, const unsigned short* __restrict__ afr,
    const float* __restrict__ bias, unsigned short* __restrict__ out)
{
    const int tid  = threadIdx.x;
    const int wave = tid >> 6;
    const int lane = tid & 63;
    const int col  = lane & 15;
    const int kg   = lane >> 4;
    const int wg   = blockIdx.x * 4 + wave;      // 0..3455
    const int row  = wg / 3;
    const int wseg = wg - row * 3;
    const int t    = row / DD;
    const int d    = row - t * DD;
    const int w0   = wseg * 32;

    int wn[2];
    wn[0] = w0 + col;
    wn[1] = w0 + 16 + col;
    int voff[2][3];
    #pragma unroll
    for (int nt = 0; nt < 2; nt++)
        #pragma unroll
        for (int dwi = 0; dwi < 3; dwi++) {
            int wc = wn[nt] + dwi - 1;
            wc = min(max(wc, 0), WW - 1);
            voff[nt][dwi] = wc * 64 + kg * 8;
        }

    f32x4 acc[4][2];
    #pragma unroll
    for (int fhi = 0; fhi < 4; fhi++)
        #pragma unroll
        for (int nt = 0; nt < 2; nt++)
            acc[fhi][nt] = (f32x4){0.f, 0.f, 0.f, 0.f};

    const int tb = t * PLANE;
    #pragma unroll
    for (int ddi = 0; ddi < 3; ddi++) {
        int dr = d + ddi - 1;
        dr = min(max(dr, 0), DD - 1);
        const unsigned short* rp = in + (size_t)(tb + dr * WW) * 64;
        #pragma unroll
        for (int dwi = 0; dwi < 3; dwi++) {
            const int tap = ddi * 3 + dwi;
            #pragma unroll
            for (int cl = 0; cl < 2; cl++) {
                const bf16x8 b0 = *(const bf16x8*)(rp + voff[0][dwi] + cl * 32);
                const bf16x8 b1 = *(const bf16x8*)(rp + voff[1][dwi] + cl * 32);
                const unsigned short* ap = afr + (size_t)((tap * 2 + cl) * 4) * 512 + lane * 8;
                #pragma unroll
                for (int fhi = 0; fhi < 4; fhi++) {
                    const bf16x8 a = *(const bf16x8*)(ap + fhi * 512);
                    acc[fhi][0] = __builtin_amdgcn_mfma_f32_16x16x32_bf16(a, b0, acc[fhi][0], 0, 0, 0);
                    acc[fhi][1] = __builtin_amdgcn_mfma_f32_16x16x32_bf16(a, b1, acc[fhi][1], 0, 0, 0);
                }
            }
        }
    }

    const int pbase = tb + d * WW;
    #pragma unroll
    for (int fhi = 0; fhi < 4; fhi++) {
        const float4 bv = *(const float4*)(bias + fhi * 16 + kg * 4);
        #pragma unroll
        for (int nt = 0; nt < 2; nt++) {
            const int p = pbase + wn[nt];
            const unsigned int lo = cvt_pk_bf16(fmaxf(acc[fhi][nt][0] + bv.x, 0.f),
                                                fmaxf(acc[fhi][nt][1] + bv.y, 0.f));
            const unsigned int hi = cvt_pk_bf16(fmaxf(acc[fhi][nt][2] + bv.z, 0.f),
                                                fmaxf(acc[fhi][nt][3] + bv.w, 0.f));
            *(uint2*)(out + (size_t)p * 64 + fhi * 16 + kg * 4) = make_uint2(lo, hi);
        }
    }
}

// ===========================================================================
// Temporal 3-tap conv via MFMA, wrap pad, bias+relu. bf16 [p][c] in/out.
// ===========================================================================
__global__ __launch_bounds__(256) void conv_tm_mfma(
    const unsigned short* __restrict__ in, const unsigned short* __restrict__ afr,
    const float* __restrict__ bias, unsigned short* __restrict__ out)
{
    const int tid  = threadIdx.x;
    const int wave = tid >> 6;
    const int lane = tid & 63;
    const int col  = lane & 15;
    const int kg   = lane >> 4;
    const int wg   = blockIdx.x * 4 + wave;      // 0..3455
    const int t    = wg / 288;
    const int seg  = wg - t * 288;
    const int p20  = seg * 32;

    f32x4 acc[4][2];
    #pragma unroll
    for (int fhi = 0; fhi < 4; fhi++)
        #pragma unroll
        for (int nt = 0; nt < 2; nt++)
            acc[fhi][nt] = (f32x4){0.f, 0.f, 0.f, 0.f};

    #pragma unroll
    for (int dt = 0; dt < 3; dt++) {
        const int tsrc = (t + dt + 11) % 12;
        const unsigned short* bp = in + (size_t)(tsrc * PLANE + p20 + col) * 64 + kg * 8;
        #pragma unroll
        for (int cl = 0; cl < 2; cl++) {
            const bf16x8 b0 = *(const bf16x8*)(bp + cl * 32);
            const bf16x8 b1 = *(const bf16x8*)(bp + 16 * 64 + cl * 32);
            const unsigned short* ap = afr + (size_t)((dt * 2 + cl) * 4) * 512 + lane * 8;
            #pragma unroll
            for (int fhi = 0; fhi < 4; fhi++) {
                const bf16x8 a = *(const bf16x8*)(ap + fhi * 512);
                acc[fhi][0] = __builtin_amdgcn_mfma_f32_16x16x32_bf16(a, b0, acc[fhi][0], 0, 0, 0);
                acc[fhi][1] = __builtin_amdgcn_mfma_f32_16x16x32_bf16(a, b1, acc[fhi][1], 0, 0, 0);
            }
        }
    }

    const int pbase = t * PLANE + p20;
    #pragma unroll
    for (int fhi = 0; fhi < 4; fhi++) {
        const float4 bv = *(const float4*)(bias + fhi * 16 + kg * 4);
        #pragma unroll
        for (int nt = 0; nt < 2; nt++) {
            const int p = pbase + nt * 16 + col;
            const unsigned int lo = cvt_pk_bf16(fmaxf(acc[fhi][nt][0] + bv.x, 0.f),
                                                fmaxf(acc[fhi][nt][1] + bv.y, 0.f));
            const unsigned int hi = cvt_pk_bf16(fmaxf(acc[fhi][nt][2] + bv.z, 0.f),
                                                fmaxf(acc[fhi][nt][3] + bv.w, 0.f));
            *(uint2*)(out + (size_t)p * 64 + fhi * 16 + kg * 4) = make_uint2(lo, hi);
        }
    }
}

// ===========================================================================
// LRU via MFMA, v4: all activation I/O bf16 [p][c] (x, hT, out); hnew f32
// [c][p] staged through an LDS transpose tile for coalesced float4 stores.
// Block = 64 consecutive positions x all 64 channels (4 waves: 2 p-groups x
// 2 fhi-pairs). Epilogue h comes from hT (bf16) - no f32 h reads at all.
// ===========================================================================
__global__ __launch_bounds__(256) void lru_mfma4(
    const unsigned short* __restrict__ x, const unsigned short* __restrict__ hT,
    const unsigned short* __restrict__ awp,
    const float* __restrict__ bih, const float* __restrict__ bh,
    unsigned short* __restrict__ out, float* __restrict__ hnew)
{
    __shared__ float lds_h[64][68];   // [f][p_local], 68 pad: 16B-aligned rows
    const int tid  = threadIdx.x;
    const int wave = tid >> 6;
    const int lane = tid & 63;
    const int col  = lane & 15;
    const int kg   = lane >> 4;
    const int p0b  = blockIdx.x * 64;
    const int pgrp = wave >> 1;              // 0/1 -> 32-position group
    const int p0   = p0b + pgrp * 32;
    const int fp   = (wave & 1) * 2;         // fhi pair base

    // B fragments: one dwordx4 load each.
    bf16x8 bx[2][2], bh8[2][2];
    #pragma unroll
    for (int nt = 0; nt < 2; nt++) {
        const size_t pb = (size_t)(p0 + nt * 16 + col) * 64 + kg * 8;
        #pragma unroll
        for (int ks = 0; ks < 2; ks++) {
            bx[ks][nt]  = *(const bf16x8*)(x  + pb + ks * 32);
            bh8[ks][nt] = *(const bf16x8*)(hT + pb + ks * 32);
        }
    }

    #pragma unroll
    for (int ff = 0; ff < 2; ff++) {
        const int fhi = fp + ff;
        const int f0  = fhi * 16 + kg * 4;
        const unsigned short* ap = awp + (size_t)(fhi * 12) * 2 * 512 + lane * 8;

        // biases hoisted out of nt loop
        const float4 b0v = *(const float4*)(bih + 0*F + f0);
        const float4 b1v = *(const float4*)(bih + 1*F + f0);
        const float4 b2v = *(const float4*)(bih + 2*F + f0);
        const float4 b3v = *(const float4*)(bih + 3*F + f0);
        const float4 b4v = *(const float4*)(bih + 4*F + f0);
        const float4 b5v = *(const float4*)(bih + 5*F + f0);
        const float4 bhv = *(const float4*)(bh + f0);
        const float b0a[4] = {b0v.x, b0v.y, b0v.z, b0v.w};
        const float b1a[4] = {b1v.x, b1v.y, b1v.z, b1v.w};
        const float b2a[4] = {b2v.x, b2v.y, b2v.z, b2v.w};
        const float b3a[4] = {b3v.x, b3v.y, b3v.z, b3v.w};
        const float b4a[4] = {b4v.x, b4v.y, b4v.z, b4v.w};
        const float b5a[4] = {b5v.x, b5v.y, b5v.z, b5v.w};
        const float bha[4] = {bhv.x, bhv.y, bhv.z, bhv.w};

        #pragma unroll
        for (int nt = 0; nt < 2; nt++) {
            const int p  = p0 + nt * 16 + col;
            const int pl = pgrp * 32 + nt * 16 + col;

            // epilogue operands issued early
            const bf16x4 xv4 = *(const bf16x4*)(x  + (size_t)p * 64 + f0);
            const bf16x4 hv4 = *(const bf16x4*)(hT + (size_t)p * 64 + f0);

            f32x4 acc[12];
            #pragma unroll
            for (int t = 0; t < 12; t++)
                acc[t] = (f32x4){0.f, 0.f, 0.f, 0.f};

            #pragma unroll
            for (int t = 0; t < 12; t++) {
                #pragma unroll
                for (int ks = 0; ks < 2; ks++) {
                    const bf16x8 a = *(const bf16x8*)(ap + (t * 2 + ks) * 512);
                    acc[t] = __builtin_amdgcn_mfma_f32_16x16x32_bf16(
                        a, (t < 6 ? bx[ks][nt] : bh8[ks][nt]), acc[t], 0, 0, 0);
                }
            }

            float o[4];
            #pragma unroll
            for (int r = 0; r < 4; r++) {
                const float ri = sigmoidf_fast(acc[0][r] + b0a[r] + acc[6][r]);
                const float rh = sigmoidf_fast(acc[1][r] + b1a[r] + acc[7][r]);
                const float zi = sigmoidf_fast(acc[2][r] + b2a[r] + acc[8][r]);
                const float zh = sigmoidf_fast(acc[3][r] + b3a[r] + acc[9][r]);
                const float ci = tanhf_fast(acc[5][r] + b5a[r] + rh * (acc[11][r] + bha[r]));
                const float ch = tanhf_fast(ri * (acc[4][r] + b4a[r]) + acc[10][r]);
                const float xf = bf2f((unsigned short)xv4[r]);
                const float hf = bf2f((unsigned short)hv4[r]);
                o[r] = zi * ch + (1.0f - zi) * xf;
                lds_h[f0 + r][pl] = zh * ci + (1.0f - zh) * hf;
            }
            const unsigned int lo = cvt_pk_bf16(o[0], o[1]);
            const unsigned int hi = cvt_pk_bf16(o[2], o[3]);
            *(uint2*)(out + (size_t)p * 64 + f0) = make_uint2(lo, hi);
        }
    }

    __syncthreads();
    // coalesced hnew write-out: 16 lanes x float4 = 256B per f-row
    const int fr = tid >> 4;         // 0..15
    const int ps = tid & 15;         // 0..15
    #pragma unroll
    for (int k = 0; k < 4; k++) {
        const int f = fr + k * 16;
        const float4 v = *(const float4*)&lds_h[f][ps * 4];
        *(float4*)&hnew[(size_t)f * SP + p0b + ps * 4] = v;
    }
}

// ===========================================================================
// Final temporal conv, COUT=2, no relu. bf16 [p][c] in, f32 [j][p] out.
// ===========================================================================
__global__ __launch_bounds__(256) void conv_tm_out(
    const unsigned short* __restrict__ in, const float* __restrict__ wgt,
    const float* __restrict__ bias, float* __restrict__ out)
{
    const int p  = blockIdx.x * 256 + threadIdx.x;
    const int t  = p / PLANE;
    const int p2 = p - t * PLANE;
    const size_t im = (size_t)(((t + 11) % 12) * PLANE + p2) * 64;
    const size_t ic = (size_t)p * 64;
    const size_t ip = (size_t)(((t + 1) % 12) * PLANE + p2) * 64;

    float acc0 = 0.f, acc1 = 0.f;
    for (int c0 = 0; c0 < 64; c0 += 8) {
        const bf16x8 vm = *(const bf16x8*)(in + im + c0);
        const bf16x8 vc = *(const bf16x8*)(in + ic + c0);
        const bf16x8 vp = *(const bf16x8*)(in + ip + c0);
        #pragma unroll
        for (int jj = 0; jj < 8; jj++) {
            const int c = c0 + jj;
            const float fm = bf2f((unsigned short)vm[jj]);
            const float fc = bf2f((unsigned short)vc[jj]);
            const float fp = bf2f((unsigned short)vp[jj]);
            const float* w0 = wgt + (0 * 64 + c) * 3;
            const float* w1 = wgt + (1 * 64 + c) * 3;
            acc0 += fm * w0[0] + fc * w0[1] + fp * w0[2];
            acc1 += fm * w1[0] + fc * w1[1] + fp * w1[2];
        }
    }
    out[0 * SP + p] = acc0 + bias[0];
    out[1 * SP + p] = acc1 + bias[1];
}

// ===========================================================================
extern "C" void kernel_launch(void* const* d_in, const int* in_sizes, int n_in,
                              void* d_out, int out_size, void* d_ws, size_t ws_size,
                              hipStream_t stream) {
    const float* x       = (const float*)d_in[0];
    const float* h1      = (const float*)d_in[1];
    const float* h2      = (const float*)d_in[2];
    const float* win_w1  = (const float*)d_in[3];
    const float* win_b1  = (const float*)d_in[4];
    const float* win_w2  = (const float*)d_in[5];
    const float* win_b2  = (const float*)d_in[6];
    const float* r1_wih  = (const float*)d_in[7];
    const float* r1_bih  = (const float*)d_in[8];
    const float* r1_whh  = (const float*)d_in[9];
    const float* r1_bh   = (const float*)d_in[10];
    const float* wbt_w1  = (const float*)d_in[11];
    const float* wbt_b1  = (const float*)d_in[12];
    const float* wbt_w2  = (const float*)d_in[13];
    const float* wbt_b2  = (const float*)d_in[14];
    const float* r2_wih  = (const float*)d_in[15];
    const float* r2_bih  = (const float*)d_in[16];
    const float* r2_whh  = (const float*)d_in[17];
    const float* r2_bh   = (const float*)d_in[18];
    const float* wout_w1 = (const float*)d_in[19];
    const float* wout_b1 = (const float*)d_in[20];
    const float* wout_w2 = (const float*)d_in[21];
    const float* wout_b2 = (const float*)d_in[22];

    float* eta_out = (float*)d_out;                       // 2*SP
    float* h1n_out = eta_out + 2 * SP;                    // 64*SP f32 [c][p]
    float* h2n_out = h1n_out + F * SP;

    // workspace: 3 bf16 [p][c] buffers (A, B, hT) + weight fragments
    unsigned short* bufA = (unsigned short*)d_ws;         // SP*64 u16
    unsigned short* bufB = bufA + (size_t)SP * 64;
    unsigned short* hT   = bufB + (size_t)SP * 64;        // shared h1/h2 transpose
    unsigned short* lru1_awp = hT + (size_t)SP * 64;      // 49152
    unsigned short* lru2_awp = lru1_awp + 49152;          // 49152
    unsigned short* wbt1_f   = lru2_awp + 49152;          // 36864
    unsigned short* wout1_f  = wbt1_f + 36864;            // 36864
    unsigned short* win2_f   = wout1_f + 36864;           // 12288
    unsigned short* wbt2_f   = win2_f + 12288;            // 12288
    float*          win1_p   = (float*)(wbt2_f + 12288);  // 2304 f32

    const dim3 blk(256);

    // --- repacks ---
    repack_lru_frag<<<192, blk, 0, stream>>>(r1_wih, r1_whh, lru1_awp);
    repack_lru_frag<<<192, blk, 0, stream>>>(r2_wih, r2_whh, lru2_awp);
    repack_sp_frag<<<144, blk, 0, stream>>>(wbt_w1, wbt1_f);
    repack_sp_frag<<<144, blk, 0, stream>>>(wout_w1, wout1_f);
    repack_tm_frag<<<48, blk, 0, stream>>>(win_w2, win2_f);
    repack_tm_frag<<<48, blk, 0, stream>>>(wbt_w2, wbt2_f);
    repack_sp4<<<9, blk, 0, stream>>>(win_w1, win1_p);

    const dim3 gIn(SP / 256, 4);     // conv_spatial_in, NF=16
    const dim3 gM(864);              // 3456 waves (sp/tm mfma)
    const dim3 gL(SP / 64);          // lru_mfma4: 64 pos/block
    const dim3 gT(SP / 64);          // transpose_h

    // block 1 (win): 4 -> 64
    transpose_h<<<gT, blk, 0, stream>>>(h1, hT);
    conv_spatial_in<<<gIn, blk, 0, stream>>>(x, win1_p, win_b1, bufA);
    conv_tm_mfma<<<gM, blk, 0, stream>>>(bufA, win2_f, win_b2, bufB);
    // LRU 1
    lru_mfma4<<<gL, blk, 0, stream>>>(bufB, hT, lru1_awp, r1_bih, r1_bh,
                                      bufA, h1n_out);
    transpose_h<<<gT, blk, 0, stream>>>(h2, hT);
    // block 2 (wbt)
    conv_sp_mfma<<<gM, blk, 0, stream>>>(bufA, wbt1_f, wbt_b1, bufB);
    conv_tm_mfma<<<gM, blk, 0, stream>>>(bufB, wbt2_f, wbt_b2, bufA);
    // LRU 2
    lru_mfma4<<<gL, blk, 0, stream>>>(bufA, hT, lru2_awp, r2_bih, r2_bh,
                                      bufB, h2n_out);
    // block 3 (wout): spatial -> 2-channel temporal, no relu
    conv_sp_mfma<<<gM, blk, 0, stream>>>(bufB, wout1_f, wout_b1, bufA);
    conv_tm_out<<<dim3(SP / 256), blk, 0, stream>>>(
        bufA, wout_w2, wout_b2, eta_out);
}

// Round 7
// 260.694 us; speedup vs baseline: 1.2020x; 1.2020x over previous
//
#include <hip/hip_runtime.h>

#define TT 12
#define DD 96
#define WW 96
#define PLANE (DD*WW)      // 9216
#define SP (TT*PLANE)      // 110592
#define F 64

typedef short bf16x8 __attribute__((ext_vector_type(8)));
typedef short bf16x4 __attribute__((ext_vector_type(4)));
typedef float f32x4  __attribute__((ext_vector_type(4)));

__device__ __forceinline__ float sigmoidf_fast(float x){
    return 1.0f / (1.0f + __expf(-x));
}
__device__ __forceinline__ float tanhf_fast(float x){
    x = fminf(15.0f, fmaxf(-15.0f, x));
    float e = __expf(2.0f * x);
    return (e - 1.0f) / (e + 1.0f);
}
__device__ __forceinline__ unsigned short f2bf(float x){
    unsigned int u = __float_as_uint(x);
    u = (u + 0x7FFFu + ((u >> 16) & 1u)) >> 16;   // RNE
    return (unsigned short)u;
}
__device__ __forceinline__ float bf2f(unsigned short u){
    return __uint_as_float(((unsigned int)u) << 16);
}
// HW packed f32x2 -> bf16x2 (RNE), 1 instr
__device__ __forceinline__ unsigned int cvt_pk_bf16(float lo, float hi){
    unsigned int r;
    asm("v_cvt_pk_bf16_f32 %0, %1, %2" : "=v"(r) : "v"(lo), "v"(hi));
    return r;
}

// ===========================================================================
// h transpose: f32 [c][p] -> bf16 [p][c]. LDS 64x65 f32 tile.
// ===========================================================================
__global__ __launch_bounds__(256) void transpose_h(
    const float* __restrict__ h, unsigned short* __restrict__ hT)
{
    __shared__ float tile[64 * 65];
    const int tid  = threadIdx.x;
    const int wv   = tid >> 6;
    const int lane = tid & 63;
    const int p0   = blockIdx.x * 64;

    #pragma unroll
    for (int cc = 0; cc < 16; cc++) {
        const int c = cc * 4 + wv;
        tile[lane * 65 + c] = h[(size_t)c * SP + p0 + lane];
    }
    __syncthreads();
    #pragma unroll
    for (int k = 0; k < 2; k++) {
        const int p  = (tid >> 3) + k * 32;
        const int c0 = (tid & 7) * 8;
        bf16x8 v;
        #pragma unroll
        for (int i = 0; i < 8; i++)
            v[i] = (short)f2bf(tile[p * 65 + c0 + i]);
        *(bf16x8*)(hT + (size_t)(p0 + p) * 64 + c0) = v;
    }
}

// ===========================================================================
// Repack kernels (every call; tiny).
// ===========================================================================
__global__ __launch_bounds__(256) void repack_lru_frag(
    const float* __restrict__ wih, const float* __restrict__ whh,
    unsigned short* __restrict__ awp)
{
    const int idx  = blockIdx.x * 256 + threadIdx.x;  // 49152
    const int j    = idx & 7;
    const int lane = (idx >> 3) & 63;
    const int frag = idx >> 9;
    const int ks   = frag & 1;
    const int t    = (frag >> 1) % 12;
    const int fhi  = frag / 24;
    const int g    = (t < 6) ? t : t - 6;
    const int m    = g * 64 + fhi * 16 + (lane & 15);
    const int kk   = ks * 32 + (lane >> 4) * 8 + j;
    const float v  = (t < 6) ? wih[m * F + kk] : whh[m * F + kk];
    awp[idx] = f2bf(v);
}

__global__ __launch_bounds__(256) void repack_sp_frag(
    const float* __restrict__ wgt, unsigned short* __restrict__ afr)
{
    const int idx  = blockIdx.x * 256 + threadIdx.x;  // 36864
    const int j    = idx & 7;
    const int lane = (idx >> 3) & 63;
    const int frag = idx >> 9;
    const int fhi  = frag & 3;
    const int cl   = (frag >> 2) & 1;
    const int tap  = frag >> 3;
    const int f    = fhi * 16 + (lane & 15);
    const int c    = cl * 32 + (lane >> 4) * 8 + j;
    afr[idx] = f2bf(wgt[(f * 64 + c) * 9 + tap]);
}

__global__ __launch_bounds__(256) void repack_tm_frag(
    const float* __restrict__ wgt, unsigned short* __restrict__ afr)
{
    const int idx  = blockIdx.x * 256 + threadIdx.x;  // 12288
    const int j    = idx & 7;
    const int lane = (idx >> 3) & 63;
    const int frag = idx >> 9;
    const int fhi  = frag & 3;
    const int cl   = (frag >> 2) & 1;
    const int dt   = frag >> 3;
    const int f    = fhi * 16 + (lane & 15);
    const int c    = cl * 32 + (lane >> 4) * 8 + j;
    afr[idx] = f2bf(wgt[(f * 64 + c) * 3 + dt]);
}

__global__ __launch_bounds__(256) void repack_sp4(
    const float* __restrict__ wgt, float* __restrict__ wp)
{
    const int idx = blockIdx.x * 256 + threadIdx.x;  // 2304
    if (idx >= 4 * 9 * 64) return;
    const int f = idx & 63;
    const int tap = (idx >> 6) % 9;
    const int c = idx / (9 * 64);
    wp[idx] = wgt[((f * 4) + c) * 9 + tap];
}

// ===========================================================================
// First conv: CIN=4, f32 [c][p] input, scalar FMA, bf16 [p][c] output, relu.
// ===========================================================================
__global__ __launch_bounds__(256) void conv_spatial_in(
    const float* __restrict__ x, const float* __restrict__ wp,
    const float* __restrict__ bias, unsigned short* __restrict__ out)
{
    const int p  = blockIdx.x * 256 + threadIdx.x;
    const int f0 = blockIdx.y * 16;
    const int t  = p / PLANE;
    const int r  = p - t * PLANE;
    const int d  = r / WW;
    const int w  = r - d * WW;
    const int dm = (d > 0    ? d - 1 : 0);
    const int dp = (d < DD-1 ? d + 1 : DD-1);
    const int wm = (w > 0    ? w - 1 : 0);
    const int wpx= (w < WW-1 ? w + 1 : WW-1);

    float acc[16];
    #pragma unroll
    for (int j = 0; j < 16; j++) acc[j] = 0.f;

    const int base = t * PLANE;
    for (int c = 0; c < 4; c++) {
        const float* ip = x + c * SP + base;
        const float v0 = ip[dm*WW+wm], v1 = ip[dm*WW+w], v2 = ip[dm*WW+wpx];
        const float v3 = ip[d *WW+wm], v4 = ip[d *WW+w], v5 = ip[d *WW+wpx];
        const float v6 = ip[dp*WW+wm], v7 = ip[dp*WW+w], v8 = ip[dp*WW+wpx];
        const float* wr = wp + c * 9 * 64 + f0;
        #pragma unroll
        for (int j = 0; j < 16; j++) {
            acc[j] += v0*wr[0*64+j] + v1*wr[1*64+j] + v2*wr[2*64+j]
                    + v3*wr[3*64+j] + v4*wr[4*64+j] + v5*wr[5*64+j]
                    + v6*wr[6*64+j] + v7*wr[7*64+j] + v8*wr[8*64+j];
        }
    }
    unsigned int pk[4];
    #pragma unroll
    for (int q = 0; q < 4; q++) {
        const float a = fmaxf(acc[q*2+0] + bias[f0 + q*2+0], 0.f);
        const float b = fmaxf(acc[q*2+1] + bias[f0 + q*2+1], 0.f);
        pk[q] = cvt_pk_bf16(a, b);
    }
    *(uint4*)(out + (size_t)p * 64 + f0) = make_uint4(pk[0], pk[1], pk[2], pk[3]);
    unsigned int pk2[4];
    #pragma unroll
    for (int q = 0; q < 4; q++) {
        const float a = fmaxf(acc[8 + q*2+0] + bias[f0 + 8 + q*2+0], 0.f);
        const float b = fmaxf(acc[8 + q*2+1] + bias[f0 + 8 + q*2+1], 0.f);
        pk2[q] = cvt_pk_bf16(a, b);
    }
    *(uint4*)(out + (size_t)p * 64 + f0 + 8) = make_uint4(pk2[0], pk2[1], pk2[2], pk2[3]);
}

// ===========================================================================
// Spatial 3x3 conv via MFMA, edge clamp, bias+relu. bf16 [p][c] in/out.
// ===========================================================================
__global__ __launch_bounds__(256) void conv_sp_mfma(
    const unsigned short* __restrict__ in, const unsigned short* __restrict__ afr,
    const float* __restrict__ bias, unsigned short* __restrict__ out)
{
    const int tid  = threadIdx.x;
    const int wave = tid >> 6;
    const int lane = tid & 63;
    const int col  = lane & 15;
    const int kg   = lane >> 4;
    const int wg   = blockIdx.x * 4 + wave;      // 0..3455
    const int row  = wg / 3;
    const int wseg = wg - row * 3;
    const int t    = row / DD;
    const int d    = row - t * DD;
    const int w0   = wseg * 32;

    int wn[2];
    wn[0] = w0 + col;
    wn[1] = w0 + 16 + col;
    int voff[2][3];
    #pragma unroll
    for (int nt = 0; nt < 2; nt++)
        #pragma unroll
        for (int dwi = 0; dwi < 3; dwi++) {
            int wc = wn[nt] + dwi - 1;
            wc = min(max(wc, 0), WW - 1);
            voff[nt][dwi] = wc * 64 + kg * 8;
        }

    f32x4 acc[4][2];
    #pragma unroll
    for (int fhi = 0; fhi < 4; fhi++)
        #pragma unroll
        for (int nt = 0; nt < 2; nt++)
            acc[fhi][nt] = (f32x4){0.f, 0.f, 0.f, 0.f};

    const int tb = t * PLANE;
    #pragma unroll
    for (int ddi = 0; ddi < 3; ddi++) {
        int dr = d + ddi - 1;
        dr = min(max(dr, 0), DD - 1);
        const unsigned short* rp = in + (size_t)(tb + dr * WW) * 64;
        #pragma unroll
        for (int dwi = 0; dwi < 3; dwi++) {
            const int tap = ddi * 3 + dwi;
            #pragma unroll
            for (int cl = 0; cl < 2; cl++) {
                const bf16x8 b0 = *(const bf16x8*)(rp + voff[0][dwi] + cl * 32);
                const bf16x8 b1 = *(const bf16x8*)(rp + voff[1][dwi] + cl * 32);
                const unsigned short* ap = afr + (size_t)((tap * 2 + cl) * 4) * 512 + lane * 8;
                #pragma unroll
                for (int fhi = 0; fhi < 4; fhi++) {
                    const bf16x8 a = *(const bf16x8*)(ap + fhi * 512);
                    acc[fhi][0] = __builtin_amdgcn_mfma_f32_16x16x32_bf16(a, b0, acc[fhi][0], 0, 0, 0);
                    acc[fhi][1] = __builtin_amdgcn_mfma_f32_16x16x32_bf16(a, b1, acc[fhi][1], 0, 0, 0);
                }
            }
        }
    }

    const int pbase = tb + d * WW;
    #pragma unroll
    for (int fhi = 0; fhi < 4; fhi++) {
        const float4 bv = *(const float4*)(bias + fhi * 16 + kg * 4);
        #pragma unroll
        for (int nt = 0; nt < 2; nt++) {
            const int p = pbase + wn[nt];
            const unsigned int lo = cvt_pk_bf16(fmaxf(acc[fhi][nt][0] + bv.x, 0.f),
                                                fmaxf(acc[fhi][nt][1] + bv.y, 0.f));
            const unsigned int hi = cvt_pk_bf16(fmaxf(acc[fhi][nt][2] + bv.z, 0.f),
                                                fmaxf(acc[fhi][nt][3] + bv.w, 0.f));
            *(uint2*)(out + (size_t)p * 64 + fhi * 16 + kg * 4) = make_uint2(lo, hi);
        }
    }
}

// ===========================================================================
// Temporal 3-tap conv via MFMA, wrap pad, bias+relu. bf16 [p][c] in/out.
// ===========================================================================
__global__ __launch_bounds__(256) void conv_tm_mfma(
    const unsigned short* __restrict__ in, const unsigned short* __restrict__ afr,
    const float* __restrict__ bias, unsigned short* __restrict__ out)
{
    const int tid  = threadIdx.x;
    const int wave = tid >> 6;
    const int lane = tid & 63;
    const int col  = lane & 15;
    const int kg   = lane >> 4;
    const int wg   = blockIdx.x * 4 + wave;      // 0..3455
    const int t    = wg / 288;
    const int seg  = wg - t * 288;
    const int p20  = seg * 32;

    f32x4 acc[4][2];
    #pragma unroll
    for (int fhi = 0; fhi < 4; fhi++)
        #pragma unroll
        for (int nt = 0; nt < 2; nt++)
            acc[fhi][nt] = (f32x4){0.f, 0.f, 0.f, 0.f};

    #pragma unroll
    for (int dt = 0; dt < 3; dt++) {
        const int tsrc = (t + dt + 11) % 12;
        const unsigned short* bp = in + (size_t)(tsrc * PLANE + p20 + col) * 64 + kg * 8;
        #pragma unroll
        for (int cl = 0; cl < 2; cl++) {
            const bf16x8 b0 = *(const bf16x8*)(bp + cl * 32);
            const bf16x8 b1 = *(const bf16x8*)(bp + 16 * 64 + cl * 32);
            const unsigned short* ap = afr + (size_t)((dt * 2 + cl) * 4) * 512 + lane * 8;
            #pragma unroll
            for (int fhi = 0; fhi < 4; fhi++) {
                const bf16x8 a = *(const bf16x8*)(ap + fhi * 512);
                acc[fhi][0] = __builtin_amdgcn_mfma_f32_16x16x32_bf16(a, b0, acc[fhi][0], 0, 0, 0);
                acc[fhi][1] = __builtin_amdgcn_mfma_f32_16x16x32_bf16(a, b1, acc[fhi][1], 0, 0, 0);
            }
        }
    }

    const int pbase = t * PLANE + p20;
    #pragma unroll
    for (int fhi = 0; fhi < 4; fhi++) {
        const float4 bv = *(const float4*)(bias + fhi * 16 + kg * 4);
        #pragma unroll
        for (int nt = 0; nt < 2; nt++) {
            const int p = pbase + nt * 16 + col;
            const unsigned int lo = cvt_pk_bf16(fmaxf(acc[fhi][nt][0] + bv.x, 0.f),
                                                fmaxf(acc[fhi][nt][1] + bv.y, 0.f));
            const unsigned int hi = cvt_pk_bf16(fmaxf(acc[fhi][nt][2] + bv.z, 0.f),
                                                fmaxf(acc[fhi][nt][3] + bv.w, 0.f));
            *(uint2*)(out + (size_t)p * 64 + fhi * 16 + kg * 4) = make_uint2(lo, hi);
        }
    }
}

// ===========================================================================
// LRU via MFMA, v5: gate-split dual orientation.
//  - even gates (t=0,2,4,6,8,10) feed `out`: normal mfma(W, data) -> C[f,p];
//    lane holds 4 consecutive f at one p -> 8B bf16 store to out[p][c].
//  - odd gates (t=1,3,5,7,9,11) feed `hnew`: swapped mfma(data, W) -> C[p,f];
//    lane holds 4 consecutive p at one f -> float4 store to hnew[c][p], and
//    the h blend is one coalesced float4 load from f32 h[c][p].
// A/B fragment lane maps are identical on gfx950 16x16x32, so the SAME awp
// fragments and the SAME x/hT data registers serve both orientations.
// No LDS, no barrier. 96 MFMAs/wave as before.
// ===========================================================================
__global__ __launch_bounds__(256) void lru_mfma5(
    const unsigned short* __restrict__ x, const unsigned short* __restrict__ hT,
    const float* __restrict__ h,
    const unsigned short* __restrict__ awp,
    const float* __restrict__ bih, const float* __restrict__ bh,
    unsigned short* __restrict__ out, float* __restrict__ hnew)
{
    const int tid  = threadIdx.x;
    const int wave = tid >> 6;
    const int lane = tid & 63;
    const int col  = lane & 15;
    const int kg   = lane >> 4;
    const int wg   = blockIdx.x * 4 + wave;   // 0..6911
    const int p0   = (wg >> 1) * 32;
    const int fp   = (wg & 1) * 2;            // fhi pair base

    // data fragments: one dwordx4 load each (dual-use as A or B operand)
    bf16x8 bx[2][2], bh8[2][2];
    #pragma unroll
    for (int nt = 0; nt < 2; nt++) {
        const size_t pb = (size_t)(p0 + nt * 16 + col) * 64 + kg * 8;
        #pragma unroll
        for (int ks = 0; ks < 2; ks++) {
            bx[ks][nt]  = *(const bf16x8*)(x  + pb + ks * 32);
            bh8[ks][nt] = *(const bf16x8*)(hT + pb + ks * 32);
        }
    }

    #pragma unroll
    for (int ff = 0; ff < 2; ff++) {
        const int fhi  = fp + ff;
        const int f0   = fhi * 16 + kg * 4;   // out-path channel base
        const int fcol = fhi * 16 + col;      // hnew-path channel
        const unsigned short* ap = awp + (size_t)(fhi * 12) * 2 * 512 + lane * 8;

        // out-path biases (per-f float4)
        const float4 b0v = *(const float4*)(bih + 0*F + f0);
        const float4 b2v = *(const float4*)(bih + 2*F + f0);
        const float4 b4v = *(const float4*)(bih + 4*F + f0);
        const float b0a[4] = {b0v.x, b0v.y, b0v.z, b0v.w};
        const float b2a[4] = {b2v.x, b2v.y, b2v.z, b2v.w};
        const float b4a[4] = {b4v.x, b4v.y, b4v.z, b4v.w};
        // hnew-path biases (scalar per lane: one f each)
        const float bih1f = bih[1*F + fcol];
        const float bih3f = bih[3*F + fcol];
        const float bih5f = bih[5*F + fcol];
        const float bhf   = bh[fcol];

        #pragma unroll
        for (int nt = 0; nt < 2; nt++) {
            const int p    = p0 + nt * 16 + col;        // out-path position
            const int prow = p0 + nt * 16 + kg * 4;     // hnew-path position base

            // epilogue operands issued early (hide under MFMAs)
            const bf16x4 xv4 = *(const bf16x4*)(x + (size_t)p * 64 + f0);
            const float4 h4  = *(const float4*)(h + (size_t)fcol * SP + prow);

            f32x4 acc_o[6], acc_h[6];
            #pragma unroll
            for (int j = 0; j < 6; j++) {
                acc_o[j] = (f32x4){0.f, 0.f, 0.f, 0.f};
                acc_h[j] = (f32x4){0.f, 0.f, 0.f, 0.f};
            }

            #pragma unroll
            for (int t = 0; t < 12; t++) {
                const int j = t >> 1;
                #pragma unroll
                for (int ks = 0; ks < 2; ks++) {
                    const bf16x8 a = *(const bf16x8*)(ap + (t * 2 + ks) * 512);
                    const bf16x8 dat = (t < 6) ? bx[ks][nt] : bh8[ks][nt];
                    if ((t & 1) == 0)
                        acc_o[j] = __builtin_amdgcn_mfma_f32_16x16x32_bf16(a, dat, acc_o[j], 0, 0, 0);
                    else
                        acc_h[j] = __builtin_amdgcn_mfma_f32_16x16x32_bf16(dat, a, acc_h[j], 0, 0, 0);
                }
            }

            // ---- out epilogue: C[f,p], r indexes 4 consecutive f ----
            float o[4];
            #pragma unroll
            for (int r = 0; r < 4; r++) {
                const float ri = sigmoidf_fast(acc_o[0][r] + b0a[r] + acc_o[3][r]);
                const float zi = sigmoidf_fast(acc_o[1][r] + b2a[r] + acc_o[4][r]);
                const float ch = tanhf_fast(ri * (acc_o[2][r] + b4a[r]) + acc_o[5][r]);
                const float xf = bf2f((unsigned short)xv4[r]);
                o[r] = zi * ch + (1.0f - zi) * xf;
            }
            *(uint2*)(out + (size_t)p * 64 + f0) =
                make_uint2(cvt_pk_bf16(o[0], o[1]), cvt_pk_bf16(o[2], o[3]));

            // ---- hnew epilogue: C[p,f], r indexes 4 consecutive p ----
            float4 hn;
            float hnr[4];
            const float hsrc[4] = {h4.x, h4.y, h4.z, h4.w};
            #pragma unroll
            for (int r = 0; r < 4; r++) {
                const float rh = sigmoidf_fast(acc_h[0][r] + bih1f + acc_h[3][r]);
                const float zh = sigmoidf_fast(acc_h[1][r] + bih3f + acc_h[4][r]);
                const float ci = tanhf_fast(acc_h[2][r] + bih5f + rh * (acc_h[5][r] + bhf));
                hnr[r] = zh * ci + (1.0f - zh) * hsrc[r];
            }
            hn.x = hnr[0]; hn.y = hnr[1]; hn.z = hnr[2]; hn.w = hnr[3];
            *(float4*)(hnew + (size_t)fcol * SP + prow) = hn;
        }
    }
}

// ===========================================================================
// Final temporal conv, COUT=2, no relu. bf16 [p][c] in, f32 [j][p] out.
// ===========================================================================
__global__ __launch_bounds__(256) void conv_tm_out(
    const unsigned short* __restrict__ in, const float* __restrict__ wgt,
    const float* __restrict__ bias, float* __restrict__ out)
{
    const int p  = blockIdx.x * 256 + threadIdx.x;
    const int t  = p / PLANE;
    const int p2 = p - t * PLANE;
    const size_t im = (size_t)(((t + 11) % 12) * PLANE + p2) * 64;
    const size_t ic = (size_t)p * 64;
    const size_t ip = (size_t)(((t + 1) % 12) * PLANE + p2) * 64;

    float acc0 = 0.f, acc1 = 0.f;
    for (int c0 = 0; c0 < 64; c0 += 8) {
        const bf16x8 vm = *(const bf16x8*)(in + im + c0);
        const bf16x8 vc = *(const bf16x8*)(in + ic + c0);
        const bf16x8 vp = *(const bf16x8*)(in + ip + c0);
        #pragma unroll
        for (int jj = 0; jj < 8; jj++) {
            const int c = c0 + jj;
            const float fm = bf2f((unsigned short)vm[jj]);
            const float fc = bf2f((unsigned short)vc[jj]);
            const float fp = bf2f((unsigned short)vp[jj]);
            const float* w0 = wgt + (0 * 64 + c) * 3;
            const float* w1 = wgt + (1 * 64 + c) * 3;
            acc0 += fm * w0[0] + fc * w0[1] + fp * w0[2];
            acc1 += fm * w1[0] + fc * w1[1] + fp * w1[2];
        }
    }
    out[0 * SP + p] = acc0 + bias[0];
    out[1 * SP + p] = acc1 + bias[1];
}

// ===========================================================================
extern "C" void kernel_launch(void* const* d_in, const int* in_sizes, int n_in,
                              void* d_out, int out_size, void* d_ws, size_t ws_size,
                              hipStream_t stream) {
    const float* x       = (const float*)d_in[0];
    const float* h1      = (const float*)d_in[1];
    const float* h2      = (const float*)d_in[2];
    const float* win_w1  = (const float*)d_in[3];
    const float* win_b1  = (const float*)d_in[4];
    const float* win_w2  = (const float*)d_in[5];
    const float* win_b2  = (const float*)d_in[6];
    const float* r1_wih  = (const float*)d_in[7];
    const float* r1_bih  = (const float*)d_in[8];
    const float* r1_whh  = (const float*)d_in[9];
    const float* r1_bh   = (const float*)d_in[10];
    const float* wbt_w1  = (const float*)d_in[11];
    const float* wbt_b1  = (const float*)d_in[12];
    const float* wbt_w2  = (const float*)d_in[13];
    const float* wbt_b2  = (const float*)d_in[14];
    const float* r2_wih  = (const float*)d_in[15];
    const float* r2_bih  = (const float*)d_in[16];
    const float* r2_whh  = (const float*)d_in[17];
    const float* r2_bh   = (const float*)d_in[18];
    const float* wout_w1 = (const float*)d_in[19];
    const float* wout_b1 = (const float*)d_in[20];
    const float* wout_w2 = (const float*)d_in[21];
    const float* wout_b2 = (const float*)d_in[22];

    float* eta_out = (float*)d_out;                       // 2*SP
    float* h1n_out = eta_out + 2 * SP;                    // 64*SP f32 [c][p]
    float* h2n_out = h1n_out + F * SP;

    // workspace: 3 bf16 [p][c] buffers (A, B, hT) + weight fragments
    unsigned short* bufA = (unsigned short*)d_ws;         // SP*64 u16
    unsigned short* bufB = bufA + (size_t)SP * 64;
    unsigned short* hT   = bufB + (size_t)SP * 64;        // shared h1/h2 transpose
    unsigned short* lru1_awp = hT + (size_t)SP * 64;      // 49152
    unsigned short* lru2_awp = lru1_awp + 49152;          // 49152
    unsigned short* wbt1_f   = lru2_awp + 49152;          // 36864
    unsigned short* wout1_f  = wbt1_f + 36864;            // 36864
    unsigned short* win2_f   = wout1_f + 36864;           // 12288
    unsigned short* wbt2_f   = win2_f + 12288;            // 12288
    float*          win1_p   = (float*)(wbt2_f + 12288);  // 2304 f32

    const dim3 blk(256);

    // --- repacks ---
    repack_lru_frag<<<192, blk, 0, stream>>>(r1_wih, r1_whh, lru1_awp);
    repack_lru_frag<<<192, blk, 0, stream>>>(r2_wih, r2_whh, lru2_awp);
    repack_sp_frag<<<144, blk, 0, stream>>>(wbt_w1, wbt1_f);
    repack_sp_frag<<<144, blk, 0, stream>>>(wout_w1, wout1_f);
    repack_tm_frag<<<48, blk, 0, stream>>>(win_w2, win2_f);
    repack_tm_frag<<<48, blk, 0, stream>>>(wbt_w2, wbt2_f);
    repack_sp4<<<9, blk, 0, stream>>>(win_w1, win1_p);

    const dim3 gIn(SP / 256, 4);     // conv_spatial_in, NF=16
    const dim3 gM(864);              // 3456 waves (sp/tm mfma)
    const dim3 gL(1728);             // 6912 waves (lru_mfma5)
    const dim3 gT(SP / 64);          // transpose_h

    // block 1 (win): 4 -> 64
    transpose_h<<<gT, blk, 0, stream>>>(h1, hT);
    conv_spatial_in<<<gIn, blk, 0, stream>>>(x, win1_p, win_b1, bufA);
    conv_tm_mfma<<<gM, blk, 0, stream>>>(bufA, win2_f, win_b2, bufB);
    // LRU 1
    lru_mfma5<<<gL, blk, 0, stream>>>(bufB, hT, h1, lru1_awp, r1_bih, r1_bh,
                                      bufA, h1n_out);
    transpose_h<<<gT, blk, 0, stream>>>(h2, hT);
    // block 2 (wbt)
    conv_sp_mfma<<<gM, blk, 0, stream>>>(bufA, wbt1_f, wbt_b1, bufB);
    conv_tm_mfma<<<gM, blk, 0, stream>>>(bufB, wbt2_f, wbt_b2, bufA);
    // LRU 2
    lru_mfma5<<<gL, blk, 0, stream>>>(bufA, hT, h2, lru2_awp, r2_bih, r2_bh,
                                      bufB, h2n_out);
    // block 3 (wout): spatial -> 2-channel temporal, no relu
    conv_sp_mfma<<<gM, blk, 0, stream>>>(bufB, wout1_f, wout_b1, bufA);
    conv_tm_out<<<dim3(SP / 256), blk, 0, stream>>>(
        bufA, wout_w2, wout_b2, eta_out);
}